// Round 1
// baseline (4829.752 us; speedup 1.0000x reference)
//
#include <hip/hip_runtime.h>
#include <hip/hip_bf16.h>
#include <math.h>

#define L_ 4
#define B_ 64
#define N_ 511
#define D_ 256
#define H_ 8
#define DFF_ 512
#define S_ 512
#define HD_ 32
#define BW_ 7
#define BS_ (B_*S_)   // 32768 rows

// ---------------------------------------------------------------------------
// build x = [game_token, patch_emb[cell_states]] : (B, S, D)
__global__ __launch_bounds__(256) void build_x(const int* __restrict__ cs,
                                               const float* __restrict__ patch,
                                               const float* __restrict__ game,
                                               float* __restrict__ x)
{
    int idx = blockIdx.x * 256 + threadIdx.x;       // over B*S*D/4 float4s
    int n4 = BS_ * D_ / 4;
    if (idx >= n4) return;
    int row = idx / (D_ / 4);                        // b*S + s
    int c4  = idx % (D_ / 4);
    int s = row & (S_ - 1);
    float4 v;
    if (s == 0) {
        v = ((const float4*)game)[c4];
    } else {
        int b = row / S_;
        int cell = cs[b * N_ + s - 1];
        v = ((const float4*)(patch + cell * D_))[c4];
    }
    ((float4*)x)[idx] = v;
}

// ---------------------------------------------------------------------------
// et8[b][q][k] = (q>0 && k>0) ? et[b][q-1][k-1] : 3   (3 -> bias 0)
__global__ __launch_bounds__(256) void build_et8(const int* __restrict__ et,
                                                 unsigned char* __restrict__ et8)
{
    long idx = (long)blockIdx.x * 256 + threadIdx.x;  // over B*S*S
    int k = (int)(idx & (S_ - 1));
    long rem = idx >> 9;                              // b*S + q
    int q = (int)(rem & (S_ - 1));
    int b = (int)(rem >> 9);
    unsigned char v = 3;
    if (q > 0 && k > 0) {
        v = (unsigned char)et[((long)b * N_ + (q - 1)) * N_ + (k - 1)];
    }
    et8[idx] = v;
}

// ---------------------------------------------------------------------------
// LayerNorm: one block (256 threads) per row of D=256
__global__ __launch_bounds__(256) void ln_kernel(const float* __restrict__ in,
                                                 float* __restrict__ out,
                                                 const float* __restrict__ gw,
                                                 const float* __restrict__ bw)
{
    __shared__ float red[8];
    long row = blockIdx.x;
    int t = threadIdx.x;
    float v = in[row * D_ + t];
    float s = v;
    #pragma unroll
    for (int o = 32; o >= 1; o >>= 1) s += __shfl_xor(s, o);
    int wid = t >> 6, lane = t & 63;
    if (lane == 0) red[wid] = s;
    __syncthreads();
    float mean = (red[0] + red[1] + red[2] + red[3]) * (1.f / 256.f);
    float d = v - mean;
    float s2 = d * d;
    #pragma unroll
    for (int o = 32; o >= 1; o >>= 1) s2 += __shfl_xor(s2, o);
    if (lane == 0) red[4 + wid] = s2;
    __syncthreads();
    float var = (red[4] + red[5] + red[6] + red[7]) * (1.f / 256.f);
    float rstd = rsqrtf(var + 1e-5f);
    out[row * D_ + t] = d * rstd * gw[t] + bw[t];
}

// ---------------------------------------------------------------------------
// C[M,N] = A[M,K] @ W[N,K]^T + bias[N] (+R) (relu?)
// 64x64 tile, BK=16, 256 threads, 4x4 micro-tile
template<bool RELU, bool RES>
__global__ __launch_bounds__(256) void gemm_kernel(const float* __restrict__ A,
                                                   const float* __restrict__ W,
                                                   const float* __restrict__ bias,
                                                   const float* __restrict__ Rp,
                                                   float* __restrict__ C,
                                                   int M, int N, int K)
{
    __shared__ float As[16][68];
    __shared__ float Ws[16][68];
    int t = threadIdx.x;
    int col0 = blockIdx.x * 64;
    int row0 = blockIdx.y * 64;
    int lr = t >> 2;
    int lc = (t & 3) * 4;
    int ty = t >> 4, tx = t & 15;
    float acc[4][4] = {};
    const float* Aptr = A + (long)(row0 + lr) * K + lc;
    const float* Wptr = W + (long)(col0 + lr) * K + lc;
    for (int k0 = 0; k0 < K; k0 += 16) {
        float4 a4 = *(const float4*)(Aptr + k0);
        float4 w4 = *(const float4*)(Wptr + k0);
        __syncthreads();
        As[lc + 0][lr] = a4.x; As[lc + 1][lr] = a4.y;
        As[lc + 2][lr] = a4.z; As[lc + 3][lr] = a4.w;
        Ws[lc + 0][lr] = w4.x; Ws[lc + 1][lr] = w4.y;
        Ws[lc + 2][lr] = w4.z; Ws[lc + 3][lr] = w4.w;
        __syncthreads();
        #pragma unroll
        for (int kk = 0; kk < 16; kk++) {
            float4 av = *(const float4*)&As[kk][ty * 4];
            float4 wv = *(const float4*)&Ws[kk][tx * 4];
            float a[4] = {av.x, av.y, av.z, av.w};
            float w[4] = {wv.x, wv.y, wv.z, wv.w};
            #pragma unroll
            for (int i = 0; i < 4; i++)
                #pragma unroll
                for (int j = 0; j < 4; j++)
                    acc[i][j] += a[i] * w[j];
        }
    }
    float4 bv = *(const float4*)&bias[col0 + tx * 4];
    float bb[4] = {bv.x, bv.y, bv.z, bv.w};
    #pragma unroll
    for (int i = 0; i < 4; i++) {
        long r = row0 + ty * 4 + i;
        long cidx = r * N + col0 + tx * 4;
        float4 res;
        float vals[4];
        #pragma unroll
        for (int j = 0; j < 4; j++) vals[j] = acc[i][j] + bb[j];
        if (RES) {
            float4 rv = *(const float4*)&Rp[cidx];
            vals[0] += rv.x; vals[1] += rv.y; vals[2] += rv.z; vals[3] += rv.w;
        }
        if (RELU) {
            #pragma unroll
            for (int j = 0; j < 4; j++) vals[j] = fmaxf(vals[j], 0.f);
        }
        res.x = vals[0]; res.y = vals[1]; res.z = vals[2]; res.w = vals[3];
        *(float4*)&C[cidx] = res;
    }
}

// ---------------------------------------------------------------------------
// Attention: block = (b, h, 32 q-rows). Two-pass softmax, score tile in LDS.
#define SCP 520
__global__ __launch_bounds__(256) void attn_kernel(const float* __restrict__ qkv,
                                                   const unsigned char* __restrict__ et8,
                                                   const float* __restrict__ eemb,
                                                   float* __restrict__ o)
{
    __shared__ float sc[32][SCP];     // 66560 B
    __shared__ float Qs[32][36];      //  4608 B
    __shared__ float KVs[64][36];     //  9216 B
    __shared__ float mrow[32];        //   128 B  -> total 80512 B (2 blocks/CU)

    int bid = blockIdx.x;
    int h  = bid & 7;
    int qt = (bid >> 3) & 15;
    int b  = bid >> 7;
    int t  = threadIdx.x;

    float ebt[4];
    ebt[0] = eemb[0 * H_ + h];
    ebt[1] = eemb[1 * H_ + h];
    ebt[2] = eemb[2 * H_ + h];
    ebt[3] = 0.f;
    const float rscale = 0.17677669529663687f;   // 1/sqrt(32)

    // stage Q tile (rows qt*32..+31, cols h*32..+31)
    {
        int r = t >> 3;
        int c = (t & 7) * 4;
        const float* src = qkv + ((long)(b * S_ + qt * 32 + r)) * (3 * D_) + h * 32 + c;
        float4 v = *(const float4*)src;
        *(float4*)&Qs[r][c] = v;
    }

    int ty = t >> 4;    // q-pair index 0..15 -> rows 2ty, 2ty+1
    int tx = t & 15;    // k-group of 4

    // ---- phase 2: scores = QK^T * rscale + bias -> sc
    for (int kt = 0; kt < 8; kt++) {
        __syncthreads();
        {
            int r = t >> 2;
            int c = (t & 3) * 8;
            const float* src = qkv + ((long)(b * S_ + kt * 64 + r)) * (3 * D_) + D_ + h * 32 + c;
            float4 v0 = *(const float4*)src;
            float4 v1 = *(const float4*)(src + 4);
            *(float4*)&KVs[r][c] = v0;
            *(float4*)&KVs[r][c + 4] = v1;
        }
        __syncthreads();
        float acc[2][4] = {};
        #pragma unroll
        for (int d = 0; d < 32; d += 4) {
            float4 q0 = *(const float4*)&Qs[2 * ty][d];
            float4 q1 = *(const float4*)&Qs[2 * ty + 1][d];
            #pragma unroll
            for (int j = 0; j < 4; j++) {
                float4 kv = *(const float4*)&KVs[4 * tx + j][d];
                acc[0][j] += q0.x * kv.x + q0.y * kv.y + q0.z * kv.z + q0.w * kv.w;
                acc[1][j] += q1.x * kv.x + q1.y * kv.y + q1.z * kv.z + q1.w * kv.w;
            }
        }
        #pragma unroll
        for (int i = 0; i < 2; i++) {
            int q = 2 * ty + i;
            const unsigned char* ep = et8 + ((long)(b * S_ + qt * 32 + q)) * S_ + kt * 64 + 4 * tx;
            uchar4 e4 = *(const uchar4*)ep;
            float4 sv;
            sv.x = acc[i][0] * rscale + ebt[e4.x];
            sv.y = acc[i][1] * rscale + ebt[e4.y];
            sv.z = acc[i][2] * rscale + ebt[e4.z];
            sv.w = acc[i][3] * rscale + ebt[e4.w];
            *(float4*)&sc[q][kt * 64 + 4 * tx] = sv;
        }
    }
    __syncthreads();

    // ---- phase 3: row softmax (8 threads per row, rows within one wave)
    {
        int r = t >> 3, g = t & 7;
        float m = -1e30f;
        #pragma unroll 8
        for (int i = 0; i < 64; i++) m = fmaxf(m, sc[r][g + 8 * i]);
        #pragma unroll
        for (int off = 1; off < 8; off <<= 1) m = fmaxf(m, __shfl_xor(m, off));
        float sum = 0.f;
        #pragma unroll 8
        for (int i = 0; i < 64; i++) {
            int k = g + 8 * i;
            float p = __expf(sc[r][k] - m);
            sc[r][k] = p;
            sum += p;
        }
        #pragma unroll
        for (int off = 1; off < 8; off <<= 1) sum += __shfl_xor(sum, off);
        if (g == 0) mrow[r] = 1.f / sum;
    }
    __syncthreads();

    // ---- phase 4: O = P @ V
    int qg = t >> 4;     // rows 2qg, 2qg+1
    int dg = t & 15;     // cols 2dg, 2dg+1
    float oacc[2][2] = {};
    for (int kt = 0; kt < 8; kt++) {
        __syncthreads();
        {
            int r = t >> 2;
            int c = (t & 3) * 8;
            const float* src = qkv + ((long)(b * S_ + kt * 64 + r)) * (3 * D_) + 2 * D_ + h * 32 + c;
            float4 v0 = *(const float4*)src;
            float4 v1 = *(const float4*)(src + 4);
            *(float4*)&KVs[r][c] = v0;
            *(float4*)&KVs[r][c + 4] = v1;
        }
        __syncthreads();
        #pragma unroll
        for (int k4 = 0; k4 < 64; k4 += 4) {
            float4 p0 = *(const float4*)&sc[2 * qg][kt * 64 + k4];
            float4 p1 = *(const float4*)&sc[2 * qg + 1][kt * 64 + k4];
            float pa0[4] = {p0.x, p0.y, p0.z, p0.w};
            float pa1[4] = {p1.x, p1.y, p1.z, p1.w};
            #pragma unroll
            for (int j = 0; j < 4; j++) {
                float2 v2 = *(const float2*)&KVs[k4 + j][2 * dg];
                oacc[0][0] += pa0[j] * v2.x;
                oacc[0][1] += pa0[j] * v2.y;
                oacc[1][0] += pa1[j] * v2.x;
                oacc[1][1] += pa1[j] * v2.y;
            }
        }
    }
    {
        float l0 = mrow[2 * qg], l1 = mrow[2 * qg + 1];
        long base = ((long)(b * S_ + qt * 32)) * D_ + h * 32;
        float2 w0 = make_float2(oacc[0][0] * l0, oacc[0][1] * l0);
        float2 w1 = make_float2(oacc[1][0] * l1, oacc[1][1] * l1);
        *(float2*)(o + base + (2 * qg) * D_ + 2 * dg) = w0;
        *(float2*)(o + base + (2 * qg + 1) * D_ + 2 * dg) = w1;
    }
}

// ---------------------------------------------------------------------------
// Head: g = x[:,0,:]; o1 = relu(g@fc1^T+b); pol = o1@pol^T+b; val = tanh(o1@val^T+b)
__global__ __launch_bounds__(64) void head_kernel(const float* __restrict__ x,
                                                  const float* __restrict__ fc1w,
                                                  const float* __restrict__ fc1b,
                                                  const float* __restrict__ polw,
                                                  const float* __restrict__ polb,
                                                  const float* __restrict__ valw,
                                                  const float* __restrict__ valb,
                                                  float* __restrict__ out)
{
    __shared__ float o1[64];
    int b = blockIdx.x;
    int t = threadIdx.x;
    const float* g = x + (long)b * S_ * D_;    // row s=0
    float acc = fc1b[t];
    for (int k = 0; k < D_; k++) acc += g[k] * fc1w[t * D_ + k];
    o1[t] = fmaxf(acc, 0.f);
    __syncthreads();
    if (t < BW_) {
        float a = polb[t];
        for (int k = 0; k < 64; k++) a += o1[k] * polw[t * 64 + k];
        out[b * BW_ + t] = a;
    } else if (t == BW_) {
        float a = valb[0];
        for (int k = 0; k < 64; k++) a += o1[k] * valw[k];
        out[B_ * BW_ + b] = tanhf(a);
    }
}

// ---------------------------------------------------------------------------
extern "C" void kernel_launch(void* const* d_in, const int* in_sizes, int n_in,
                              void* d_out, int out_size, void* d_ws, size_t ws_size,
                              hipStream_t stream)
{
    const int*   cs    = (const int*)d_in[0];
    const int*   etm   = (const int*)d_in[1];
    const float* patch = (const float*)d_in[2];
    const float* game  = (const float*)d_in[3];
    const float* eemb  = (const float*)d_in[4];
    const float* in_w  = (const float*)d_in[5];
    const float* in_b  = (const float*)d_in[6];
    const float* out_w = (const float*)d_in[7];
    const float* out_b = (const float*)d_in[8];
    const float* ff1_w = (const float*)d_in[9];
    const float* ff1_b = (const float*)d_in[10];
    const float* ff2_w = (const float*)d_in[11];
    const float* ff2_b = (const float*)d_in[12];
    const float* ln1_g = (const float*)d_in[13];
    const float* ln1_b = (const float*)d_in[14];
    const float* ln2_g = (const float*)d_in[15];
    const float* ln2_b = (const float*)d_in[16];
    const float* fc1_w = (const float*)d_in[17];
    const float* fc1_b = (const float*)d_in[18];
    const float* pol_w = (const float*)d_in[19];
    const float* pol_b = (const float*)d_in[20];
    const float* val_w = (const float*)d_in[21];
    const float* val_b = (const float*)d_in[22];
    float* out = (float*)d_out;

    float* ws = (float*)d_ws;
    float* x    = ws;                       //  8388608 f
    float* hbuf = ws + 8388608L;            //  8388608 f
    float* qkvb = ws + 16777216L;           // 25165824 f (also FF buffer)
    float* obuf = ws + 41943040L;           //  8388608 f
    unsigned char* et8 = (unsigned char*)(ws + 50331648L);   // 16777216 B

    build_x<<<8192, 256, 0, stream>>>(cs, patch, game, x);
    build_et8<<<65536, 256, 0, stream>>>(etm, et8);

    for (int i = 0; i < L_; i++) {
        ln_kernel<<<BS_, 256, 0, stream>>>(x, hbuf, ln1_g + i * D_, ln1_b + i * D_);
        gemm_kernel<false, false><<<dim3(12, 512), 256, 0, stream>>>(
            hbuf, in_w + (long)i * 768 * 256, in_b + i * 768, nullptr, qkvb, BS_, 768, 256);
        attn_kernel<<<8192, 256, 0, stream>>>(qkvb, et8, eemb, obuf);
        gemm_kernel<false, true><<<dim3(4, 512), 256, 0, stream>>>(
            obuf, out_w + (long)i * 65536, out_b + i * 256, x, x, BS_, 256, 256);
        ln_kernel<<<BS_, 256, 0, stream>>>(x, hbuf, ln2_g + i * D_, ln2_b + i * D_);
        gemm_kernel<true, false><<<dim3(8, 512), 256, 0, stream>>>(
            hbuf, ff1_w + (long)i * 131072, ff1_b + i * 512, nullptr, qkvb, BS_, 512, 256);
        gemm_kernel<false, true><<<dim3(4, 512), 256, 0, stream>>>(
            qkvb, ff2_w + (long)i * 131072, ff2_b + i * 256, x, x, BS_, 256, 512);
    }
    head_kernel<<<B_, 64, 0, stream>>>(x, fc1_w, fc1_b, pol_w, pol_b, val_w, val_b, out);
}

// Round 2
// 1755.197 us; speedup vs baseline: 2.7517x; 2.7517x over previous
//
#include <hip/hip_runtime.h>
#include <hip/hip_bf16.h>
#include <math.h>

#define L_ 4
#define B_ 64
#define N_ 511
#define D_ 256
#define H_ 8
#define DFF_ 512
#define S_ 512
#define HD_ 32
#define BW_ 7
#define BS_ (B_*S_)   // 32768 rows

typedef __attribute__((ext_vector_type(8))) short short8;   // 8 x bf16 bits
typedef __attribute__((ext_vector_type(4))) float f32x4;

__device__ inline ushort f2b(float f) {
    unsigned u = __float_as_uint(f);
    unsigned r = (u + 0x7fffu + ((u >> 16) & 1u)) >> 16;   // RNE
    return (ushort)r;
}

__device__ inline float bsel(unsigned char e, float b0, float b1, float b2) {
    return e == 0 ? b0 : (e == 1 ? b1 : (e == 2 ? b2 : 0.f));
}

// ---------------------------------------------------------------------------
// build x = [game_token, patch_emb[cell_states]] : (B, S, D) fp32
__global__ __launch_bounds__(256) void build_x(const int* __restrict__ cs,
                                               const float* __restrict__ patch,
                                               const float* __restrict__ game,
                                               float* __restrict__ x)
{
    int idx = blockIdx.x * 256 + threadIdx.x;       // over B*S*D/4 float4s
    int row = idx / (D_ / 4);                        // b*S + s
    int c4  = idx % (D_ / 4);
    int s = row & (S_ - 1);
    float4 v;
    if (s == 0) {
        v = ((const float4*)game)[c4];
    } else {
        int b = row / S_;
        int cell = cs[b * N_ + s - 1];
        v = ((const float4*)(patch + cell * D_))[c4];
    }
    ((float4*)x)[idx] = v;
}

// ---------------------------------------------------------------------------
// et8t[b][k][q] = (q>0 && k>0) ? et[b][q-1][k-1] : 3   (3 -> bias 0)
// transposed layout so attention's bias fetch is a uchar4 over q
__global__ __launch_bounds__(256) void build_et8t(const int* __restrict__ et,
                                                  unsigned char* __restrict__ et8t)
{
    __shared__ unsigned char tile[64][65];
    int bx = blockIdx.x & 7;         // k-tile
    int by = (blockIdx.x >> 3) & 7;  // q-tile
    int b  = blockIdx.x >> 6;
    int t = threadIdx.x;
    #pragma unroll
    for (int it = 0; it < 16; it++) {
        int q = by * 64 + it * 4 + (t >> 6);
        int k = bx * 64 + (t & 63);
        unsigned char v = 3;
        if (q >= 1 && k >= 1)
            v = (unsigned char)et[((size_t)b * N_ + (q - 1)) * N_ + (k - 1)];
        tile[it * 4 + (t >> 6)][t & 63] = v;
    }
    __syncthreads();
    #pragma unroll
    for (int it = 0; it < 16; it++) {
        int k = bx * 64 + it * 4 + (t >> 6);
        int ql = t & 63;
        et8t[((size_t)b * S_ + k) * S_ + by * 64 + ql] = tile[ql][it * 4 + (t >> 6)];
    }
}

// ---------------------------------------------------------------------------
// fp32 -> bf16 weight conversion
__global__ __launch_bounds__(256) void convert_f2b(const float* __restrict__ in,
                                                   ushort* __restrict__ out, int n4)
{
    int i = blockIdx.x * 256 + threadIdx.x;
    if (i >= n4) return;
    float4 v = ((const float4*)in)[i];
    ushort4 o4;
    o4.x = f2b(v.x); o4.y = f2b(v.y); o4.z = f2b(v.z); o4.w = f2b(v.w);
    ((ushort4*)out)[i] = o4;
}

// ---------------------------------------------------------------------------
// LayerNorm: one wave per row (64 lanes x float4), fp32 in -> bf16 out
__global__ __launch_bounds__(256) void ln_kernel(const float* __restrict__ in,
                                                 ushort* __restrict__ out,
                                                 const float* __restrict__ gw,
                                                 const float* __restrict__ bw)
{
    int t = threadIdx.x;
    int lane = t & 63;
    int r = t >> 6;
    size_t row = (size_t)blockIdx.x * 4 + r;
    float4 v = *(const float4*)(in + row * D_ + lane * 4);
    float s = v.x + v.y + v.z + v.w;
    #pragma unroll
    for (int o = 32; o >= 1; o >>= 1) s += __shfl_xor(s, o);
    float mean = s * (1.f / 256.f);
    float dx = v.x - mean, dy = v.y - mean, dz = v.z - mean, dw = v.w - mean;
    float s2 = dx * dx + dy * dy + dz * dz + dw * dw;
    #pragma unroll
    for (int o = 32; o >= 1; o >>= 1) s2 += __shfl_xor(s2, o);
    float rstd = rsqrtf(s2 * (1.f / 256.f) + 1e-5f);
    float4 g  = *(const float4*)(gw + lane * 4);
    float4 bb = *(const float4*)(bw + lane * 4);
    ushort4 o4;
    o4.x = f2b(dx * rstd * g.x + bb.x);
    o4.y = f2b(dy * rstd * g.y + bb.y);
    o4.z = f2b(dz * rstd * g.z + bb.z);
    o4.w = f2b(dw * rstd * g.w + bb.w);
    *(ushort4*)(out + row * D_ + lane * 4) = o4;
}

// ---------------------------------------------------------------------------
// MFMA GEMM: C[M,N] = A[M,K](bf16) @ W[N,K]^T(bf16) + bias (+R fp32) (relu?)
// block = 4 waves, tile 128x64; wave tile 32x64 (2x4 of 16x16), K-step 32.
template<int K, int N, bool RELU, bool RES, bool OUTBF>
__global__ __launch_bounds__(256) void gemm_mfma(const ushort* __restrict__ A,
                                                 const ushort* __restrict__ W,
                                                 const float* __restrict__ bias,
                                                 const float* __restrict__ R,
                                                 void* __restrict__ Cout)
{
    int t = threadIdx.x;
    int wave = t >> 6, lane = t & 63;
    int lr = lane & 15, quad = lane >> 4;
    int lk = quad * 8;
    int n0 = blockIdx.x * 64;
    int m0 = blockIdx.y * 128 + wave * 32;
    const ushort* Ap = A + (size_t)(m0 + lr) * K + lk;
    const ushort* Wp = W + (size_t)(n0 + lr) * K + lk;
    f32x4 acc[2][4];
    f32x4 zz = {0.f, 0.f, 0.f, 0.f};
    #pragma unroll
    for (int i = 0; i < 2; i++)
        #pragma unroll
        for (int j = 0; j < 4; j++) acc[i][j] = zz;

    for (int k0 = 0; k0 < K; k0 += 32) {
        short8 a0 = *(const short8*)(Ap + k0);
        short8 a1 = *(const short8*)(Ap + 16 * K + k0);
        short8 b0 = *(const short8*)(Wp + k0);
        short8 b1 = *(const short8*)(Wp + 16 * K + k0);
        short8 b2 = *(const short8*)(Wp + 32 * K + k0);
        short8 b3 = *(const short8*)(Wp + 48 * K + k0);
        acc[0][0] = __builtin_amdgcn_mfma_f32_16x16x32_bf16(a0, b0, acc[0][0], 0, 0, 0);
        acc[0][1] = __builtin_amdgcn_mfma_f32_16x16x32_bf16(a0, b1, acc[0][1], 0, 0, 0);
        acc[0][2] = __builtin_amdgcn_mfma_f32_16x16x32_bf16(a0, b2, acc[0][2], 0, 0, 0);
        acc[0][3] = __builtin_amdgcn_mfma_f32_16x16x32_bf16(a0, b3, acc[0][3], 0, 0, 0);
        acc[1][0] = __builtin_amdgcn_mfma_f32_16x16x32_bf16(a1, b0, acc[1][0], 0, 0, 0);
        acc[1][1] = __builtin_amdgcn_mfma_f32_16x16x32_bf16(a1, b1, acc[1][1], 0, 0, 0);
        acc[1][2] = __builtin_amdgcn_mfma_f32_16x16x32_bf16(a1, b2, acc[1][2], 0, 0, 0);
        acc[1][3] = __builtin_amdgcn_mfma_f32_16x16x32_bf16(a1, b3, acc[1][3], 0, 0, 0);
    }

    #pragma unroll
    for (int nt = 0; nt < 4; nt++) {
        int col = n0 + nt * 16 + lr;
        float bv = bias[col];
        #pragma unroll
        for (int mt = 0; mt < 2; mt++) {
            #pragma unroll
            for (int r = 0; r < 4; r++) {
                int row = m0 + mt * 16 + quad * 4 + r;
                size_t idx = (size_t)row * N + col;
                float v = acc[mt][nt][r] + bv;
                if (RES)  v += R[idx];
                if (RELU) v = fmaxf(v, 0.f);
                if (OUTBF) ((ushort*)Cout)[idx] = f2b(v);
                else       ((float*)Cout)[idx] = v;
            }
        }
    }
}

// ---------------------------------------------------------------------------
// repack qkv (bf16 [bs][768]) -> Qb,Kb [b,h,s,32] and Vt [b,h,32,s]
__global__ __launch_bounds__(256) void repack_qkv(const ushort* __restrict__ qkv,
                                                  ushort* __restrict__ Qb,
                                                  ushort* __restrict__ Kb,
                                                  ushort* __restrict__ Vt)
{
    __shared__ ushort vt[64][42];
    int bh = blockIdx.x;
    int b = bh >> 3, h = bh & 7;
    int t = threadIdx.x;
    for (int s0 = 0; s0 < S_; s0 += 64) {
        int s = s0 + (t >> 2);
        int c = (t & 3) * 8;
        const ushort* src = qkv + ((size_t)(b * S_ + s)) * 768 + h * 32 + c;
        uint4 qv = *(const uint4*)src;
        uint4 kv = *(const uint4*)(src + 256);
        uint4 vv = *(const uint4*)(src + 512);
        *(uint4*)(Qb + ((size_t)(bh * S_ + s)) * 32 + c) = qv;
        *(uint4*)(Kb + ((size_t)(bh * S_ + s)) * 32 + c) = kv;
        uint* dst = (uint*)&vt[s - s0][c];
        uint* pv = (uint*)&vv;
        dst[0] = pv[0]; dst[1] = pv[1]; dst[2] = pv[2]; dst[3] = pv[3];
        __syncthreads();
        int d = t >> 3, j0 = (t & 7) * 8;
        short8 w;
        #pragma unroll
        for (int j = 0; j < 8; j++) w[j] = (short)vt[j0 + j][d];
        *(short8*)(Vt + ((size_t)bh * 32 + d) * S_ + s0 + j0) = w;
        __syncthreads();
    }
}

// ---------------------------------------------------------------------------
// Flash attention with MFMA. block = (b, h, 64 q-rows); wave = 16 q-rows.
__global__ __launch_bounds__(256) void attn_mfma(const ushort* __restrict__ Qb,
                                                 const ushort* __restrict__ Kb,
                                                 const ushort* __restrict__ Vt,
                                                 const unsigned char* __restrict__ et8t,
                                                 const float* __restrict__ eemb,
                                                 ushort* __restrict__ o)
{
    __shared__ ushort pls[4][16][40];
    int t = threadIdx.x;
    int wave = t >> 6, lane = t & 63;
    int lr = lane & 15, quad = lane >> 4;
    int lk = quad * 8;
    int h  = blockIdx.x & 7;
    int qb = (blockIdx.x >> 3) & 7;
    int b  = blockIdx.x >> 6;
    int bh = b * 8 + h;
    int q0 = qb * 64 + wave * 16;
    const float rscale = 0.17677669529663687f;   // 1/sqrt(32)
    float eb0 = eemb[h], eb1 = eemb[8 + h], eb2 = eemb[16 + h];

    short8 qf = *(const short8*)(Qb + ((size_t)(bh * S_ + q0 + lr)) * 32 + lk);
    f32x4 zz = {0.f, 0.f, 0.f, 0.f};
    f32x4 o0 = zz, o1 = zz;
    float mrow[4], lrow[4];
    #pragma unroll
    for (int r = 0; r < 4; r++) { mrow[r] = -1e30f; lrow[r] = 0.f; }

    const ushort* Kp = Kb + (size_t)bh * S_ * 32 + lr * 32 + lk;
    const ushort* Vp = Vt + (size_t)bh * 32 * S_ + lr * S_ + lk;

    for (int k0 = 0; k0 < S_; k0 += 32) {
        short8 kf0 = *(const short8*)(Kp + (size_t)k0 * 32);
        short8 kf1 = *(const short8*)(Kp + (size_t)(k0 + 16) * 32);
        f32x4 s0 = __builtin_amdgcn_mfma_f32_16x16x32_bf16(qf, kf0, zz, 0, 0, 0);
        f32x4 s1 = __builtin_amdgcn_mfma_f32_16x16x32_bf16(qf, kf1, zz, 0, 0, 0);
        const unsigned char* ep = et8t + ((size_t)(b * S_ + k0 + lr)) * S_ + q0 + quad * 4;
        uchar4 e0v = *(const uchar4*)ep;
        uchar4 e1v = *(const uchar4*)(ep + 16 * S_);
        unsigned char e0a[4] = {e0v.x, e0v.y, e0v.z, e0v.w};
        unsigned char e1a[4] = {e1v.x, e1v.y, e1v.z, e1v.w};
        float p0[4], p1[4];
        #pragma unroll
        for (int r = 0; r < 4; r++) {
            float v0 = s0[r] * rscale + bsel(e0a[r], eb0, eb1, eb2);
            float v1 = s1[r] * rscale + bsel(e1a[r], eb0, eb1, eb2);
            float mx = fmaxf(v0, v1);
            mx = fmaxf(mx, __shfl_xor(mx, 1));
            mx = fmaxf(mx, __shfl_xor(mx, 2));
            mx = fmaxf(mx, __shfl_xor(mx, 4));
            mx = fmaxf(mx, __shfl_xor(mx, 8));
            float nm = fmaxf(mrow[r], mx);
            float al = __expf(mrow[r] - nm);
            mrow[r] = nm;
            float e0f = __expf(v0 - nm);
            float e1f = __expf(v1 - nm);
            float sum = e0f + e1f;
            sum += __shfl_xor(sum, 1);
            sum += __shfl_xor(sum, 2);
            sum += __shfl_xor(sum, 4);
            sum += __shfl_xor(sum, 8);
            lrow[r] = lrow[r] * al + sum;
            o0[r] *= al;
            o1[r] *= al;
            p0[r] = e0f;
            p1[r] = e1f;
        }
        #pragma unroll
        for (int r = 0; r < 4; r++) {
            pls[wave][quad * 4 + r][lr]      = f2b(p0[r]);
            pls[wave][quad * 4 + r][16 + lr] = f2b(p1[r]);
        }
        __syncthreads();
        short8 pf = *(const short8*)&pls[wave][lr][lk];
        __syncthreads();
        short8 vf0 = *(const short8*)(Vp + k0);
        short8 vf1 = *(const short8*)(Vp + 16 * S_ + k0);
        o0 = __builtin_amdgcn_mfma_f32_16x16x32_bf16(pf, vf0, o0, 0, 0, 0);
        o1 = __builtin_amdgcn_mfma_f32_16x16x32_bf16(pf, vf1, o1, 0, 0, 0);
    }

    #pragma unroll
    for (int r = 0; r < 4; r++) {
        float inv = 1.f / lrow[r];
        size_t base = (size_t)(b * S_ + q0 + quad * 4 + r) * D_ + h * 32;
        o[base + lr]      = f2b(o0[r] * inv);
        o[base + 16 + lr] = f2b(o1[r] * inv);
    }
}

// ---------------------------------------------------------------------------
// Head (fp32): g = x[:,0,:]; o1 = relu(g@fc1^T+b); pol = o1@pol^T+b; val = tanh(...)
__global__ __launch_bounds__(64) void head_kernel(const float* __restrict__ x,
                                                  const float* __restrict__ fc1w,
                                                  const float* __restrict__ fc1b,
                                                  const float* __restrict__ polw,
                                                  const float* __restrict__ polb,
                                                  const float* __restrict__ valw,
                                                  const float* __restrict__ valb,
                                                  float* __restrict__ out)
{
    __shared__ float o1[64];
    int b = blockIdx.x;
    int t = threadIdx.x;
    const float* g = x + (size_t)b * S_ * D_;
    float acc = fc1b[t];
    for (int k = 0; k < D_; k++) acc += g[k] * fc1w[t * D_ + k];
    o1[t] = fmaxf(acc, 0.f);
    __syncthreads();
    if (t < BW_) {
        float a = polb[t];
        for (int k = 0; k < 64; k++) a += o1[k] * polw[t * 64 + k];
        out[b * BW_ + t] = a;
    } else if (t == BW_) {
        float a = valb[0];
        for (int k = 0; k < 64; k++) a += o1[k] * valw[k];
        out[B_ * BW_ + b] = tanhf(a);
    }
}

// ---------------------------------------------------------------------------
extern "C" void kernel_launch(void* const* d_in, const int* in_sizes, int n_in,
                              void* d_out, int out_size, void* d_ws, size_t ws_size,
                              hipStream_t stream)
{
    const int*   cs    = (const int*)d_in[0];
    const int*   etm   = (const int*)d_in[1];
    const float* patch = (const float*)d_in[2];
    const float* game  = (const float*)d_in[3];
    const float* eemb  = (const float*)d_in[4];
    const float* in_w  = (const float*)d_in[5];
    const float* in_b  = (const float*)d_in[6];
    const float* out_w = (const float*)d_in[7];
    const float* out_b = (const float*)d_in[8];
    const float* ff1_w = (const float*)d_in[9];
    const float* ff1_b = (const float*)d_in[10];
    const float* ff2_w = (const float*)d_in[11];
    const float* ff2_b = (const float*)d_in[12];
    const float* ln1_g = (const float*)d_in[13];
    const float* ln1_b = (const float*)d_in[14];
    const float* ln2_g = (const float*)d_in[15];
    const float* ln2_b = (const float*)d_in[16];
    const float* fc1_w = (const float*)d_in[17];
    const float* fc1_b = (const float*)d_in[18];
    const float* pol_w = (const float*)d_in[19];
    const float* pol_b = (const float*)d_in[20];
    const float* val_w = (const float*)d_in[21];
    const float* val_b = (const float*)d_in[22];
    float* out = (float*)d_out;

    char* base = (char*)d_ws;
    float*  x     = (float*)(base + 0);                    // 33554432 B
    ushort* h     = (ushort*)(base + 33554432);            // 16777216 B
    ushort* qkvb  = (ushort*)(base + 50331648);            // 50331648 B (also FF buf)
    ushort* Qb    = (ushort*)(base + 100663296);           // 16777216 B
    ushort* Kb    = (ushort*)(base + 117440512);           // 16777216 B
    ushort* Vt    = (ushort*)(base + 134217728);           // 16777216 B
    ushort* ob    = (ushort*)(base + 150994944);           // 16777216 B
    unsigned char* et8t = (unsigned char*)(base + 167772160); // 16777216 B
    ushort* inwb  = (ushort*)(base + 184549376);           //  1572864 B
    ushort* outwb = (ushort*)(base + 186122240);           //   524288 B
    ushort* ff1wb = (ushort*)(base + 186646528);           //  1048576 B
    ushort* ff2wb = (ushort*)(base + 187695104);           //  1048576 B

    build_x<<<8192, 256, 0, stream>>>(cs, patch, game, x);
    build_et8t<<<4096, 256, 0, stream>>>(etm, et8t);
    convert_f2b<<<768, 256, 0, stream>>>(in_w,  inwb,  196608);
    convert_f2b<<<256, 256, 0, stream>>>(out_w, outwb, 65536);
    convert_f2b<<<512, 256, 0, stream>>>(ff1_w, ff1wb, 131072);
    convert_f2b<<<512, 256, 0, stream>>>(ff2_w, ff2wb, 131072);

    for (int i = 0; i < L_; i++) {
        ln_kernel<<<8192, 256, 0, stream>>>(x, h, ln1_g + i * D_, ln1_b + i * D_);
        gemm_mfma<256, 768, false, false, true><<<dim3(12, 256), 256, 0, stream>>>(
            h, inwb + (size_t)i * 196608, in_b + i * 768, nullptr, qkvb);
        repack_qkv<<<512, 256, 0, stream>>>(qkvb, Qb, Kb, Vt);
        attn_mfma<<<4096, 256, 0, stream>>>(Qb, Kb, Vt, et8t, eemb, ob);
        gemm_mfma<256, 256, false, true, false><<<dim3(4, 256), 256, 0, stream>>>(
            ob, outwb + (size_t)i * 65536, out_b + i * 256, x, x);
        ln_kernel<<<8192, 256, 0, stream>>>(x, h, ln2_g + i * D_, ln2_b + i * D_);
        gemm_mfma<256, 512, true, false, true><<<dim3(8, 256), 256, 0, stream>>>(
            h, ff1wb + (size_t)i * 131072, ff1_b + i * 512, nullptr, qkvb);
        gemm_mfma<512, 256, false, true, false><<<dim3(4, 256), 256, 0, stream>>>(
            qkvb, ff2wb + (size_t)i * 131072, ff2_b + i * 256, x, x);
    }
    head_kernel<<<B_, 64, 0, stream>>>(x, fc1_w, fc1_b, pol_w, pol_b, val_w, val_b, out);
}